// Round 7
// baseline (444.046 us; speedup 1.0000x reference)
//
#include <hip/hip_runtime.h>
#include <hip/hip_bf16.h>

typedef __attribute__((ext_vector_type(8))) short   bf16x8;
typedef __attribute__((ext_vector_type(4))) float   f32x4;
typedef unsigned short u16;

#define NTOK 64
#define CEMB 192
#define NH   6
#define ROWB 384   // row bytes for [64][192] bf16 tiles (kh / X)
#define VROWB 128  // row bytes for vhT [192][64] bf16

union U8 { uint4 u; bf16x8 v; };

__device__ __forceinline__ u16 f2b(float f) {
  unsigned u = __float_as_uint(f);
  unsigned r = (u + 0x7fffu + ((u >> 16) & 1u)) >> 16;  // RNE
  return (u16)r;
}

__device__ __forceinline__ unsigned cvtpk(float lo, float hi) {
  unsigned r;
  asm("v_cvt_pk_bf16_f32 %0, %1, %2" : "=v"(r) : "v"(lo), "v"(hi));
  return r;
}

__device__ __forceinline__ int swz(int row, int colbyte) {
  return colbyte ^ ((((row >> 3) ^ row) & 7) << 4);
}

// ---------------- prep: pack W^T (bf16) + gather rel_bias ----------------
__global__ void prep_kernel(const float* __restrict__ Wq, const float* __restrict__ Wk,
                            const float* __restrict__ Wv, const float* __restrict__ Wp,
                            const float* __restrict__ btab, const int* __restrict__ ridx,
                            u16* __restrict__ WT, float* __restrict__ rb) {
  int idx = blockIdx.x * 256 + threadIdx.x;
  if (idx < 4 * 36864) {
    int m = idx / 36864;
    int e = idx - m * 36864;
    int n = e / CEMB;
    int k = e - n * CEMB;
    const float* W = (m == 0) ? Wq : (m == 1) ? Wk : (m == 2) ? Wv : Wp;
    WT[idx] = f2b(W[k * CEMB + n]);          // WT[m][n][k] = W[k][n]
  } else {
    int i2 = idx - 4 * 36864;
    if (i2 < NH * 4096) {
      int h = i2 >> 12;
      int ij = i2 & 4095;
      rb[i2] = btab[ridx[ij] * NH + h];      // rb[h][i][j]
    }
  }
}

// ---------------- fused window attention, 52KB LDS -> 3 blocks/CU ----------------
__global__ __launch_bounds__(512, 6)
void wattn_kernel(const float* __restrict__ qg, const float* __restrict__ kg,
                  const float* __restrict__ vg, const float* __restrict__ maskg,
                  const float* __restrict__ bq, const float* __restrict__ bk,
                  const float* __restrict__ bv, const float* __restrict__ bp,
                  const u16* __restrict__ WT, const float* __restrict__ rb,
                  float* __restrict__ xout, float* __restrict__ attn_out) {
  __shared__ __align__(16) char smem[53248];
  char* sK  = smem;            // kh [64][192] swz -> X (aliased per round)
  char* sVT = smem + 24576;    // vhT [192][64] swz
  const int tid  = threadIdx.x;
  const int wave = tid >> 6;
  const int lane = tid & 63;
  const int l15  = lane & 15;
  const int lhi  = lane >> 4;
  char* sS = smem + 49152 + wave * 512;  // per-wave transpose scratch
  const int b   = blockIdx.x;
  const int rt  = wave & 3;              // row-tile owned by this wave
  const int par = wave >> 2;             // head parity
  const int irow = rt * 16 + lhi * 4;

  const size_t gbase = (size_t)b * 12288 + (size_t)(rt * 16 + l15) * CEMB + lhi * 8;

  // ---- projections: A-frags direct from global, weights from WT (L2) ----
  // q: wave computes qh strips of ITS 3 heads (h = 2*(s>>1)+par), kept in regs
  f32x4 qc[6];
  {
    bf16x8 qa[6];
    #pragma unroll
    for (int ks = 0; ks < 6; ++ks) {
      float4 a0 = *reinterpret_cast<const float4*>(qg + gbase + ks * 32);
      float4 a1 = *reinterpret_cast<const float4*>(qg + gbase + ks * 32 + 4);
      U8 u;
      u.u.x = cvtpk(a0.x, a0.y); u.u.y = cvtpk(a0.z, a0.w);
      u.u.z = cvtpk(a1.x, a1.y); u.u.w = cvtpk(a1.z, a1.w);
      qa[ks] = u.v;
    }
    #pragma unroll
    for (int s = 0; s < 6; ++s) {
      int strip = 4 * (s >> 1) + 2 * par + (s & 1);
      const u16* Wt = WT + (strip * 16 + l15) * CEMB + lhi * 8;
      f32x4 acc = {0.f, 0.f, 0.f, 0.f};
      #pragma unroll
      for (int ks = 0; ks < 6; ++ks)
        acc = __builtin_amdgcn_mfma_f32_16x16x32_bf16(qa[ks], *reinterpret_cast<const bf16x8*>(Wt + ks * 32), acc, 0, 0, 0);
      float bb = bq[strip * 16 + l15];
      #pragma unroll
      for (int r = 0; r < 4; ++r) qc[s][r] = (acc[r] + bb) * 0.17677669529663687f;
    }
  }
  // k -> sK, v -> sVT (C-frags written immediately; no raw staging in LDS)
  #pragma unroll
  for (int m = 1; m < 3; ++m) {
    const float* src = (m == 1) ? kg : vg;
    const float* bias = (m == 1) ? bk : bv;
    bf16x8 xa6[6];
    #pragma unroll
    for (int ks = 0; ks < 6; ++ks) {
      float4 a0 = *reinterpret_cast<const float4*>(src + gbase + ks * 32);
      float4 a1 = *reinterpret_cast<const float4*>(src + gbase + ks * 32 + 4);
      U8 u;
      u.u.x = cvtpk(a0.x, a0.y); u.u.y = cvtpk(a0.z, a0.w);
      u.u.z = cvtpk(a1.x, a1.y); u.u.w = cvtpk(a1.z, a1.w);
      xa6[ks] = u.v;
    }
    #pragma unroll
    for (int s = 0; s < 6; ++s) {
      int strip = par * 6 + s;
      const u16* Wt = WT + m * 36864 + (strip * 16 + l15) * CEMB + lhi * 8;
      f32x4 acc = {0.f, 0.f, 0.f, 0.f};
      #pragma unroll
      for (int ks = 0; ks < 6; ++ks)
        acc = __builtin_amdgcn_mfma_f32_16x16x32_bf16(xa6[ks], *reinterpret_cast<const bf16x8*>(Wt + ks * 32), acc, 0, 0, 0);
      float bb = bias[strip * 16 + l15];
      if (m == 1) {
        #pragma unroll
        for (int r = 0; r < 4; ++r) {
          int row = rt * 16 + lhi * 4 + r;
          *reinterpret_cast<u16*>(sK + row * ROWB + swz(row, (strip * 16 + l15) * 2)) = f2b(acc[r] + bb);
        }
      } else {
        int chan = strip * 16 + l15;
        #pragma unroll
        for (int r = 0; r < 4; ++r) {
          int tok = rt * 16 + lhi * 4 + r;
          *reinterpret_cast<u16*>(sVT + chan * VROWB + swz(chan, tok * 2)) = f2b(acc[r] + bb);
        }
      }
    }
  }
  __syncthreads();   // kh, vhT complete

  const float* maskw = maskg + (size_t)(b & 1023) * 4096;

  // ---- attention rounds: round ri handles head h = 2*ri + par ----
  #pragma unroll
  for (int ri = 0; ri < 3; ++ri) {
    int h = 2 * ri + par;

    // qh C-frag -> A-frag via 512B bounce (two 16x16 halves + lane select)
    #pragma unroll
    for (int r = 0; r < 4; ++r)
      *reinterpret_cast<u16*>(sS + ((lhi * 4 + r) * 16 + l15) * 2) = f2b(qc[2 * ri][r]);
    U8 h0; h0.u = *reinterpret_cast<const uint4*>(sS + l15 * 32 + (lhi & 1) * 16);
    #pragma unroll
    for (int r = 0; r < 4; ++r)
      *reinterpret_cast<u16*>(sS + ((lhi * 4 + r) * 16 + l15) * 2) = f2b(qc[2 * ri + 1][r]);
    U8 h1; h1.u = *reinterpret_cast<const uint4*>(sS + l15 * 32 + (lhi & 1) * 16);
    U8 av;
    av.u.x = (lhi >= 2) ? h1.u.x : h0.u.x;
    av.u.y = (lhi >= 2) ? h1.u.y : h0.u.y;
    av.u.z = (lhi >= 2) ? h1.u.z : h0.u.z;
    av.u.w = (lhi >= 2) ? h1.u.w : h0.u.w;
    bf16x8 aq = av.v;

    // S = qh @ kh^T
    f32x4 sv[4];
    #pragma unroll
    for (int ct = 0; ct < 4; ++ct) {
      int krow = ct * 16 + l15;
      bf16x8 bkf = *reinterpret_cast<const bf16x8*>(sK + krow * ROWB + swz(krow, h * 64 + lhi * 16));
      f32x4 z = {0.f, 0.f, 0.f, 0.f};
      sv[ct] = __builtin_amdgcn_mfma_f32_16x16x32_bf16(aq, bkf, z, 0, 0, 0);
    }

    // logits = S + rel_bias + mask
    const float* rbp = rb + h * 4096 + irow * 64 + l15;
    const float* mkp = maskw + irow * 64 + l15;
    float lg[4][4];
    #pragma unroll
    for (int ct = 0; ct < 4; ++ct)
      #pragma unroll
      for (int r = 0; r < 4; ++r)
        lg[ct][r] = sv[ct][r] + rbp[r * 64 + ct * 16] + mkp[r * 64 + ct * 16];

    // row softmax
    float pr[4][4];
    #pragma unroll
    for (int r = 0; r < 4; ++r) {
      float mx = fmaxf(fmaxf(lg[0][r], lg[1][r]), fmaxf(lg[2][r], lg[3][r]));
      mx = fmaxf(mx, __shfl_xor(mx, 1));
      mx = fmaxf(mx, __shfl_xor(mx, 2));
      mx = fmaxf(mx, __shfl_xor(mx, 4));
      mx = fmaxf(mx, __shfl_xor(mx, 8));
      float e0 = __expf(lg[0][r] - mx), e1 = __expf(lg[1][r] - mx);
      float e2 = __expf(lg[2][r] - mx), e3 = __expf(lg[3][r] - mx);
      float sum = e0 + e1 + e2 + e3;
      sum += __shfl_xor(sum, 1);
      sum += __shfl_xor(sum, 2);
      sum += __shfl_xor(sum, 4);
      sum += __shfl_xor(sum, 8);
      float inv = 1.0f / sum;
      pr[0][r] = e0 * inv; pr[1][r] = e1 * inv; pr[2][r] = e2 * inv; pr[3][r] = e3 * inv;
    }

    // attn probs -> global (final output, streaming)
    float* ap = attn_out + (((size_t)b * NH + h) * NTOK + irow) * NTOK;
    #pragma unroll
    for (int ct = 0; ct < 4; ++ct)
      #pragma unroll
      for (int r = 0; r < 4; ++r)
        ap[r * 64 + ct * 16 + l15] = pr[ct][r];

    // PV: P transposed through the same 512B bounce, V from sVT
    f32x4 xa[2];
    { f32x4 z = {0.f, 0.f, 0.f, 0.f}; xa[0] = z; xa[1] = z; }
    #pragma unroll
    for (int ks = 0; ks < 2; ++ks) {
      #pragma unroll
      for (int r = 0; r < 4; ++r)
        *reinterpret_cast<u16*>(sS + ((lhi * 4 + r) * 16 + l15) * 2) = f2b(pr[2 * ks][r]);
      U8 p0; p0.u = *reinterpret_cast<const uint4*>(sS + l15 * 32 + (lhi & 1) * 16);
      #pragma unroll
      for (int r = 0; r < 4; ++r)
        *reinterpret_cast<u16*>(sS + ((lhi * 4 + r) * 16 + l15) * 2) = f2b(pr[2 * ks + 1][r]);
      U8 p1; p1.u = *reinterpret_cast<const uint4*>(sS + l15 * 32 + (lhi & 1) * 16);
      U8 pv;
      pv.u.x = (lhi >= 2) ? p1.u.x : p0.u.x;
      pv.u.y = (lhi >= 2) ? p1.u.y : p0.u.y;
      pv.u.z = (lhi >= 2) ? p1.u.z : p0.u.z;
      pv.u.w = (lhi >= 2) ? p1.u.w : p0.u.w;
      bf16x8 pa = pv.v;
      #pragma unroll
      for (int cb = 0; cb < 2; ++cb) {
        int chan = h * 32 + cb * 16 + l15;
        bf16x8 bvf = *reinterpret_cast<const bf16x8*>(sVT + chan * VROWB + swz(chan, (ks * 32 + lhi * 8) * 2));
        xa[cb] = __builtin_amdgcn_mfma_f32_16x16x32_bf16(pa, bvf, xa[cb], 0, 0, 0);
      }
    }
    __syncthreads();   // all waves done reading kh cols [ri*64, ri*64+64)

    // X write into retired kh columns (disjoint from round ri+1 reads)
    #pragma unroll
    for (int cb = 0; cb < 2; ++cb)
      #pragma unroll
      for (int r = 0; r < 4; ++r) {
        int xrow = rt * 16 + lhi * 4 + r;
        int xcol = h * 32 + cb * 16 + l15;
        *reinterpret_cast<u16*>(sK + xrow * ROWB + swz(xrow, xcol * 2)) = f2b(xa[cb][r]);
      }
  }
  __syncthreads();   // X complete

  // ---- out = X @ Wp + bp ----
  #pragma unroll
  for (int ui = 0; ui < 3; ++ui) {
    int u2 = wave + ui * 8;        // 0..23
    int ct = u2 % 12;
    int rh = u2 / 12;
    const u16* Wt = WT + 3 * 36864 + (ct * 16 + l15) * CEMB + lhi * 8;
    f32x4 oa[2];
    { f32x4 z = {0.f, 0.f, 0.f, 0.f}; oa[0] = z; oa[1] = z; }
    #pragma unroll
    for (int ks = 0; ks < 6; ++ks) {
      bf16x8 bw = *reinterpret_cast<const bf16x8*>(Wt + ks * 32);
      #pragma unroll
      for (int rr = 0; rr < 2; ++rr) {
        int xrow = rh * 32 + rr * 16 + l15;
        bf16x8 ax = *reinterpret_cast<const bf16x8*>(sK + xrow * ROWB + swz(xrow, ks * 64 + lhi * 16));
        oa[rr] = __builtin_amdgcn_mfma_f32_16x16x32_bf16(ax, bw, oa[rr], 0, 0, 0);
      }
    }
    float bias = bp[ct * 16 + l15];
    #pragma unroll
    for (int rr = 0; rr < 2; ++rr)
      #pragma unroll
      for (int r = 0; r < 4; ++r)
        xout[((size_t)b * NTOK + rh * 32 + rr * 16 + lhi * 4 + r) * CEMB + ct * 16 + l15] = oa[rr][r] + bias;
  }
}

extern "C" void kernel_launch(void* const* d_in, const int* in_sizes, int n_in,
                              void* d_out, int out_size, void* d_ws, size_t ws_size,
                              hipStream_t stream) {
  const float* q    = (const float*)d_in[0];
  const float* k    = (const float*)d_in[1];
  const float* v    = (const float*)d_in[2];
  const float* mask = (const float*)d_in[3];
  const float* Wq   = (const float*)d_in[4];
  const float* bq   = (const float*)d_in[5];
  const float* Wk   = (const float*)d_in[6];
  const float* bk   = (const float*)d_in[7];
  const float* Wv   = (const float*)d_in[8];
  const float* bv   = (const float*)d_in[9];
  const float* Wp   = (const float*)d_in[10];
  const float* bp   = (const float*)d_in[11];
  const float* btab = (const float*)d_in[12];
  const int*   ridx = (const int*)d_in[13];

  u16*   WT = (u16*)d_ws;                               // 4 * 36864 bf16
  float* rb = (float*)((char*)d_ws + 4 * 36864 * 2);    // 6*64*64 fp32

  float* xout = (float*)d_out;
  float* attn = xout + (size_t)2048 * NTOK * CEMB;

  prep_kernel<<<672, 256, 0, stream>>>(Wq, Wk, Wv, Wp, btab, ridx, WT, rb);
  wattn_kernel<<<2048, 512, 0, stream>>>(q, k, v, mask, bq, bk, bv, bp, WT, rb, xout, attn);
}

// Round 8
// 203.920 us; speedup vs baseline: 2.1775x; 2.1775x over previous
//
#include <hip/hip_runtime.h>
#include <hip/hip_bf16.h>

typedef __attribute__((ext_vector_type(8))) short   bf16x8;
typedef __attribute__((ext_vector_type(4))) float   f32x4;
typedef unsigned short u16;

#define NTOK 64
#define CEMB 192
#define NH   6
#define ROWB 384   // row bytes for [64][192] bf16 tiles
#define VROWB 128  // row bytes for vhT [192][64] bf16

__device__ __forceinline__ u16 f2b(float f) {
  unsigned u = __float_as_uint(f);
  unsigned r = (u + 0x7fffu + ((u >> 16) & 1u)) >> 16;  // RNE
  return (u16)r;
}

__device__ __forceinline__ unsigned cvtpk(float lo, float hi) {
  unsigned r;
  asm("v_cvt_pk_bf16_f32 %0, %1, %2" : "=v"(r) : "v"(lo), "v"(hi));
  return r;
}

__device__ __forceinline__ int swz(int row, int colbyte) {
  return colbyte ^ ((((row >> 3) ^ row) & 7) << 4);
}

// ---------------- prep: pack W^T (bf16) + gather rel_bias ----------------
__global__ void prep_kernel(const float* __restrict__ Wq, const float* __restrict__ Wk,
                            const float* __restrict__ Wv, const float* __restrict__ Wp,
                            const float* __restrict__ btab, const int* __restrict__ ridx,
                            u16* __restrict__ WT, float* __restrict__ rb) {
  int idx = blockIdx.x * 256 + threadIdx.x;
  if (idx < 4 * 36864) {
    int m = idx / 36864;
    int e = idx - m * 36864;
    int n = e / CEMB;
    int k = e - n * CEMB;
    const float* W = (m == 0) ? Wq : (m == 1) ? Wk : (m == 2) ? Wv : Wp;
    WT[idx] = f2b(W[k * CEMB + n]);          // WT[m][n][k] = W[k][n]
  } else {
    int i2 = idx - 4 * 36864;
    if (i2 < NH * 4096) {
      int h = i2 >> 12;
      int ij = i2 & 4095;
      rb[i2] = btab[ridx[ij] * NH + h];      // rb[h][i][j]
    }
  }
}

// ---------------- fused window attention (R2 structure, spill-free, cvtpk) ----------------
__global__ __launch_bounds__(512, 4)
void wattn_kernel(const float* __restrict__ qg, const float* __restrict__ kg,
                  const float* __restrict__ vg, const float* __restrict__ maskg,
                  const float* __restrict__ bq, const float* __restrict__ bk,
                  const float* __restrict__ bv, const float* __restrict__ bp,
                  const u16* __restrict__ WT, const float* __restrict__ rb,
                  float* __restrict__ xout, float* __restrict__ attn_out) {
  __shared__ __align__(16) char smem[81920];
  char* sQ = smem;                 // raw q -> qh -> X (in-place per-unit)
  char* sK = smem + 24576;         // raw k -> kh
  char* sV = smem + 49152;         // raw v -> vhT [192][64]
  const int tid  = threadIdx.x;
  const int wave = tid >> 6;
  const int lane = tid & 63;
  const int l15  = lane & 15;
  const int lhi  = lane >> 4;
  char* sP = smem + 73728 + wave * 1024;   // per-wave P transpose scratch
  const int b = blockIdx.x;
  const float scale = 0.17677669529663687f;

  // ---- Phase 1: stage q,k,v fp32 -> bf16 LDS (cvtpk, packed 8B stores) ----
  {
    const size_t base = (size_t)b * NTOK * CEMB;
    #pragma unroll
    for (int m = 0; m < 3; ++m) {
      const float* src = (m == 0 ? qg : m == 1 ? kg : vg) + base;
      char* dst = (m == 0 ? sQ : m == 1 ? sK : sV);
      #pragma unroll
      for (int it = 0; it < 6; ++it) {
        int fi  = it * 512 + tid;            // float4 index 0..3071
        int row = fi / 48;
        int ce  = (fi - row * 48) * 4;
        const float4 v4 = reinterpret_cast<const float4*>(src)[fi];
        uint2 w;
        w.x = cvtpk(v4.x, v4.y);
        w.y = cvtpk(v4.z, v4.w);
        *reinterpret_cast<uint2*>(dst + row * ROWB + swz(row, ce * 2)) = w;
      }
    }
  }
  __syncthreads();

  // ---- Phase 2: three projection passes (q, k, v). 12 strips each over 8
  //      waves (waves 0-3 take 2); acc stays at 8 f32x4 -> no spill. Each
  //      epilogue overlaps the next pass's MFMAs (no barrier between them).
  #pragma unroll
  for (int m = 0; m < 3; ++m) {
    const char* Xs = (m == 0) ? sQ : (m == 1) ? sK : sV;
    const float* bias = (m == 0) ? bq : (m == 1) ? bk : bv;
    f32x4 acc[2][4];
    #pragma unroll
    for (int si = 0; si < 2; ++si) {
      int strip = wave + si * 8;
      if (strip < 12) {
        const u16* Wt = WT + m * 36864 + (strip * 16 + l15) * CEMB + lhi * 8;
        #pragma unroll
        for (int rt = 0; rt < 4; ++rt) { f32x4 z = {0.f,0.f,0.f,0.f}; acc[si][rt] = z; }
        #pragma unroll
        for (int ks = 0; ks < 6; ++ks) {
          bf16x8 bw = *reinterpret_cast<const bf16x8*>(Wt + ks * 32);
          #pragma unroll
          for (int rt = 0; rt < 4; ++rt) {
            int row = rt * 16 + l15;
            bf16x8 ax = *reinterpret_cast<const bf16x8*>(Xs + row * ROWB + swz(row, ks * 64 + lhi * 16));
            acc[si][rt] = __builtin_amdgcn_mfma_f32_16x16x32_bf16(ax, bw, acc[si][rt], 0, 0, 0);
          }
        }
      }
    }
    __syncthreads();   // raw reads of buffer m complete
    #pragma unroll
    for (int si = 0; si < 2; ++si) {
      int strip = wave + si * 8;
      if (strip < 12) {
        int c = strip * 16 + l15;
        float bval = bias[c];
        if (m == 0) {
          #pragma unroll
          for (int rt = 0; rt < 4; ++rt)
            #pragma unroll
            for (int r = 0; r < 4; ++r) {
              int row = rt * 16 + lhi * 4 + r;
              *reinterpret_cast<u16*>(sQ + row * ROWB + swz(row, c * 2)) = f2b((acc[si][rt][r] + bval) * scale);
            }
        } else if (m == 1) {
          #pragma unroll
          for (int rt = 0; rt < 4; ++rt)
            #pragma unroll
            for (int r = 0; r < 4; ++r) {
              int row = rt * 16 + lhi * 4 + r;
              *reinterpret_cast<u16*>(sK + row * ROWB + swz(row, c * 2)) = f2b(acc[si][rt][r] + bval);
            }
        } else {   // vhT[chan c][token], 4 consecutive tokens packed
          #pragma unroll
          for (int rt = 0; rt < 4; ++rt) {
            int t0 = rt * 16 + lhi * 4;
            uint2 w;
            w.x = cvtpk(acc[si][rt][0] + bval, acc[si][rt][1] + bval);
            w.y = cvtpk(acc[si][rt][2] + bval, acc[si][rt][3] + bval);
            *reinterpret_cast<uint2*>(sV + c * VROWB + swz(c, t0 * 2)) = w;
          }
        }
      }
    }
  }
  __syncthreads();   // qh/kh/vhT ready

  // ---- Phase 3: attention. unit u = wave + ui*8 -> (h = par+2ui, rt) ----
  const float* maskw = maskg + (size_t)(b & 1023) * 4096;
  const int rt   = wave & 3;
  const int irow = rt * 16 + lhi * 4;

  // mask is head-invariant for this wave's rows: hoist
  const float* mkp = maskw + irow * 64 + l15;
  float mkv[4][4];
  #pragma unroll
  for (int ct = 0; ct < 4; ++ct)
    #pragma unroll
    for (int r = 0; r < 4; ++r)
      mkv[ct][r] = mkp[r * 64 + ct * 16];

  #pragma unroll
  for (int ui = 0; ui < 3; ++ui) {
    int u = wave + ui * 8;         // 0..23
    int h = u >> 2;

    const float* rbp = rb + h * 4096 + irow * 64 + l15;
    float rbv[4][4];
    #pragma unroll
    for (int ct = 0; ct < 4; ++ct)
      #pragma unroll
      for (int r = 0; r < 4; ++r)
        rbv[ct][r] = rbp[r * 64 + ct * 16];

    // S = qh @ kh^T  (K = 32)
    int qrow = rt * 16 + l15;
    bf16x8 aq = *reinterpret_cast<const bf16x8*>(sQ + qrow * ROWB + swz(qrow, h * 64 + lhi * 16));
    f32x4 sv[4];
    #pragma unroll
    for (int ct = 0; ct < 4; ++ct) {
      int krow = ct * 16 + l15;
      bf16x8 bkf = *reinterpret_cast<const bf16x8*>(sK + krow * ROWB + swz(krow, h * 64 + lhi * 16));
      f32x4 z = {0.f, 0.f, 0.f, 0.f};
      sv[ct] = __builtin_amdgcn_mfma_f32_16x16x32_bf16(aq, bkf, z, 0, 0, 0);
    }

    float lg[4][4];
    #pragma unroll
    for (int ct = 0; ct < 4; ++ct)
      #pragma unroll
      for (int r = 0; r < 4; ++r)
        lg[ct][r] = sv[ct][r] + rbv[ct][r] + mkv[ct][r];

    float pr[4][4];
    #pragma unroll
    for (int r = 0; r < 4; ++r) {
      float mx = fmaxf(fmaxf(lg[0][r], lg[1][r]), fmaxf(lg[2][r], lg[3][r]));
      mx = fmaxf(mx, __shfl_xor(mx, 1));
      mx = fmaxf(mx, __shfl_xor(mx, 2));
      mx = fmaxf(mx, __shfl_xor(mx, 4));
      mx = fmaxf(mx, __shfl_xor(mx, 8));
      float e0 = __expf(lg[0][r] - mx), e1 = __expf(lg[1][r] - mx);
      float e2 = __expf(lg[2][r] - mx), e3 = __expf(lg[3][r] - mx);
      float sum = e0 + e1 + e2 + e3;
      sum += __shfl_xor(sum, 1);
      sum += __shfl_xor(sum, 2);
      sum += __shfl_xor(sum, 4);
      sum += __shfl_xor(sum, 8);
      float inv = 1.0f / sum;
      pr[0][r] = e0 * inv; pr[1][r] = e1 * inv; pr[2][r] = e2 * inv; pr[3][r] = e3 * inv;
    }

    // attn probs -> global (streaming final output)
    float* ap = attn_out + (((size_t)b * NH + h) * NTOK + irow) * NTOK;
    #pragma unroll
    for (int ct = 0; ct < 4; ++ct)
      #pragma unroll
      for (int r = 0; r < 4; ++r)
        ap[r * 64 + ct * 16 + l15] = pr[ct][r];

    // PV through lane-ordered per-wave P scratch (two K=32 halves)
    f32x4 xa[2];
    { f32x4 z = {0.f, 0.f, 0.f, 0.f}; xa[0] = z; xa[1] = z; }
    #pragma unroll
    for (int ks = 0; ks < 2; ++ks) {
      #pragma unroll
      for (int c = 0; c < 2; ++c)
        #pragma unroll
        for (int r = 0; r < 4; ++r) {
          int col  = c * 16 + l15;
          int kgp  = col >> 3;
          int j    = col & 7;
          int prow = lhi * 4 + r;
          *reinterpret_cast<u16*>(sP + ((kgp * 16 + prow) * 8 + j) * 2) = f2b(pr[ks * 2 + c][r]);
        }
      bf16x8 apf = *reinterpret_cast<const bf16x8*>(sP + lane * 16);
      #pragma unroll
      for (int ctv = 0; ctv < 2; ++ctv) {
        int vrow = h * 32 + ctv * 16 + l15;
        bf16x8 bvf = *reinterpret_cast<const bf16x8*>(sV + vrow * VROWB + swz(vrow, ks * 64 + lhi * 16));
        xa[ctv] = __builtin_amdgcn_mfma_f32_16x16x32_bf16(apf, bvf, xa[ctv], 0, 0, 0);
      }
    }

    // X in place over this unit's (rows, head-cols) region of sQ
    #pragma unroll
    for (int ctv = 0; ctv < 2; ++ctv)
      #pragma unroll
      for (int r = 0; r < 4; ++r) {
        int xrow = rt * 16 + lhi * 4 + r;
        int xcol = h * 32 + ctv * 16 + l15;
        *reinterpret_cast<u16*>(sQ + xrow * ROWB + swz(xrow, xcol * 2)) = f2b(xa[ctv][r]);
      }
  }
  __syncthreads();   // X complete

  // ---- Phase 4: out = X @ Wp + bp ----
  #pragma unroll
  for (int ui = 0; ui < 3; ++ui) {
    int u2 = wave + ui * 8;
    int ct = u2 % 12;
    int rh = u2 / 12;
    const u16* Wt = WT + 3 * 36864 + (ct * 16 + l15) * CEMB + lhi * 8;
    f32x4 oa[2];
    { f32x4 z = {0.f, 0.f, 0.f, 0.f}; oa[0] = z; oa[1] = z; }
    #pragma unroll
    for (int ks = 0; ks < 6; ++ks) {
      bf16x8 bw = *reinterpret_cast<const bf16x8*>(Wt + ks * 32);
      #pragma unroll
      for (int rr = 0; rr < 2; ++rr) {
        int xrow = rh * 32 + rr * 16 + l15;
        bf16x8 ax = *reinterpret_cast<const bf16x8*>(sQ + xrow * ROWB + swz(xrow, ks * 64 + lhi * 16));
        oa[rr] = __builtin_amdgcn_mfma_f32_16x16x32_bf16(ax, bw, oa[rr], 0, 0, 0);
      }
    }
    float bias = bp[ct * 16 + l15];
    #pragma unroll
    for (int rr = 0; rr < 2; ++rr)
      #pragma unroll
      for (int r = 0; r < 4; ++r)
        xout[((size_t)b * NTOK + rh * 32 + rr * 16 + lhi * 4 + r) * CEMB + ct * 16 + l15] = oa[rr][r] + bias;
  }
}

extern "C" void kernel_launch(void* const* d_in, const int* in_sizes, int n_in,
                              void* d_out, int out_size, void* d_ws, size_t ws_size,
                              hipStream_t stream) {
  const float* q    = (const float*)d_in[0];
  const float* k    = (const float*)d_in[1];
  const float* v    = (const float*)d_in[2];
  const float* mask = (const float*)d_in[3];
  const float* Wq   = (const float*)d_in[4];
  const float* bq   = (const float*)d_in[5];
  const float* Wk   = (const float*)d_in[6];
  const float* bk   = (const float*)d_in[7];
  const float* Wv   = (const float*)d_in[8];
  const float* bv   = (const float*)d_in[9];
  const float* Wp   = (const float*)d_in[10];
  const float* bp   = (const float*)d_in[11];
  const float* btab = (const float*)d_in[12];
  const int*   ridx = (const int*)d_in[13];

  u16*   WT = (u16*)d_ws;                               // 4 * 36864 bf16
  float* rb = (float*)((char*)d_ws + 4 * 36864 * 2);    // 6*64*64 fp32

  float* xout = (float*)d_out;
  float* attn = xout + (size_t)2048 * NTOK * CEMB;

  prep_kernel<<<672, 256, 0, stream>>>(Wq, Wk, Wv, Wp, btab, ridx, WT, rb);
  wattn_kernel<<<2048, 512, 0, stream>>>(q, k, v, mask, bq, bk, bv, bp, WT, rb, xout, attn);
}